// Round 1
// baseline (898.467 us; speedup 1.0000x reference)
//
#include <hip/hip_runtime.h>
#include <hip/hip_bf16.h>

typedef unsigned short u16;
typedef __bf16 bf16x8 __attribute__((ext_vector_type(8)));
typedef float f32x4 __attribute__((ext_vector_type(4)));

#define E_ 8
#define H_ 2048
#define D_ 2048
#define T_ 2048
#define N2_ 4096

__device__ __forceinline__ u16 f2bf(float f) {
    unsigned u = __builtin_bit_cast(unsigned, f);
    unsigned r = (u + 0x7FFFu + ((u >> 16) & 1u)) >> 16;
    return (u16)r;
}

typedef __attribute__((address_space(1))) const void* gptr_t;
typedef __attribute__((address_space(3))) void* lptr_t;
__device__ __forceinline__ void gload16(const void* g, void* l) {
    // async global->LDS, 16B/lane; LDS dest = wave-uniform base + lane*16
    __builtin_amdgcn_global_load_lds((gptr_t)g, (lptr_t)l, 16, 0, 0);
}

// ---------------- conversion / transpose pre-pass ----------------

__global__ __launch_bounds__(256) void k_convert_x(const float4* __restrict__ x,
                                                   ushort4* __restrict__ xb) {
    int i = blockIdx.x * 256 + threadIdx.x;   // exactly T_*H_/4 threads
    float4 v = x[i];
    ushort4 o;
    o.x = f2bf(v.x); o.y = f2bf(v.y); o.z = f2bf(v.z); o.w = f2bf(v.w);
    xb[i] = o;
}

// gate_up_w fp32 [E][H][2D] -> wP bf16 [E][4096][H]: transpose + de-interleave
// into 16-col gate/up groups:  gate d -> row ((d>>4)<<5)+(d&15),
//                              up   d -> row ((d>>4)<<5)+16+(d&15).
// This makes GEMM1 a single-B GEMM whose output n-frags alternate gate/up
// every 16 columns, so the GLU pairing is in-register (acc[i][2m]/acc[i][2m+1]).
__global__ __launch_bounds__(256) void k_tr_gateup(const float* __restrict__ w,
                                                   u16* __restrict__ wP) {
    __shared__ u16 Gs[64 * 73];
    __shared__ u16 Us[64 * 73];
    const int e = blockIdx.z, h0 = blockIdx.x * 64, d0 = blockIdx.y * 64;
    const int tid = threadIdx.x;
    {
        const int hl = tid >> 2;               // 0..63
        const int cseg = (tid & 3) * 32;       // fp32 col offset within 128
        const float* src = w + ((size_t)e * H_ + h0 + hl) * N2_ + 2 * d0 + cseg;
#pragma unroll
        for (int q = 0; q < 8; q++) {
            float4 v = *(const float4*)(src + q * 4);
            int dl = (cseg + q * 4) >> 1;      // even
            Gs[hl * 73 + dl]     = f2bf(v.x);
            Us[hl * 73 + dl]     = f2bf(v.y);
            Gs[hl * 73 + dl + 1] = f2bf(v.z);
            Us[hl * 73 + dl + 1] = f2bf(v.w);
        }
    }
    __syncthreads();
    {
        const int dl = tid >> 2;
        const int hseg = (tid & 3) * 16;
        u16 vg[16] __attribute__((aligned(16)));
        u16 vu[16] __attribute__((aligned(16)));
#pragma unroll
        for (int j = 0; j < 16; j++) {
            vg[j] = Gs[(hseg + j) * 73 + dl];
            vu[j] = Us[(hseg + j) * 73 + dl];
        }
        const int d = d0 + dl;
        const int rg = ((d >> 4) << 5) + (d & 15);
        size_t obg = ((size_t)e * N2_ + rg) * H_ + h0 + hseg;
        size_t obu = obg + (size_t)16 * H_;
        *(uint4*)&wP[obg]     = *(const uint4*)&vg[0];
        *(uint4*)&wP[obg + 8] = *(const uint4*)&vg[8];
        *(uint4*)&wP[obu]     = *(const uint4*)&vu[0];
        *(uint4*)&wP[obu + 8] = *(const uint4*)&vu[8];
    }
}

// down_w fp32 [E][D][H] -> wdT bf16 [E][H][D]  (transpose)
__global__ __launch_bounds__(256) void k_tr_down(const float* __restrict__ w,
                                                 u16* __restrict__ wdT) {
    __shared__ u16 Ts[64 * 73];
    const int e = blockIdx.z, d0 = blockIdx.x * 64, h0 = blockIdx.y * 64;
    const int tid = threadIdx.x;
    {
        const int dl = tid >> 2;
        const int hseg = (tid & 3) * 16;
        const float* src = w + ((size_t)e * D_ + d0 + dl) * H_ + h0 + hseg;
#pragma unroll
        for (int q = 0; q < 4; q++) {
            float4 v = *(const float4*)(src + q * 4);
            int hl = hseg + q * 4;
            Ts[(hl + 0) * 73 + dl] = f2bf(v.x);
            Ts[(hl + 1) * 73 + dl] = f2bf(v.y);
            Ts[(hl + 2) * 73 + dl] = f2bf(v.z);
            Ts[(hl + 3) * 73 + dl] = f2bf(v.w);
        }
    }
    __syncthreads();
    {
        const int hl = tid >> 2;
        const int dseg = (tid & 3) * 16;
        u16 vd[16] __attribute__((aligned(16)));
#pragma unroll
        for (int j = 0; j < 16; j++) vd[j] = Ts[hl * 73 + dseg + j];
        size_t ob = ((size_t)e * H_ + h0 + hl) * D_ + d0 + dseg;
        *(uint4*)&wdT[ob]     = *(const uint4*)&vd[0];
        *(uint4*)&wdT[ob + 8] = *(const uint4*)&vd[8];
    }
}

// ---------------- 256x256 / BK=64 / 8-wave / 8-phase GEMM machinery --------
//
// LDS per matrix: 2 bufs x 256 rows x 64 u16 (row = 8 chunks of 16B), chunk
// swizzle c_phys = c ^ (r&7)  (pre-swizzled global source, swizzled ds_read).
// Wave grid 2Mx4N: wave owns 128 rows x 64 cols -> acc[8][4] f32x4 (128 VGPR).
// Per K-tile 4 phases (mh,nh quadrants); a-frags loaded at ph(mh0)/ph(mh1),
// b-frags for both n-halves cached in regs (B's last LDS read = phase 2).
// Stage schedule (half-tile = 128 rows = 2 gload16/lane per phase):
//   ph1: buf1.A0(kt 2i+1)  ph2: buf1.A1  ph3: buf0.B0(kt 2i+2)  ph4: buf0.B1
//   ph5: buf0.A0(kt 2i+2)  ph6: buf0.A1  ph7: buf1.B0(kt 2i+3)  ph8: buf1.B1
// s_waitcnt vmcnt(4) ONLY at ph4/ph8 (each phase issues 2 loads/lane; the
// 4 allowed outstanding are exactly the 2 newest phases' stages). Never
// vmcnt(0) in the loop -> loads stay in flight across barriers (T3+T4).
// setprio(1) around each 16-MFMA cluster (T5; pays only with phase split).

#define UNROLL _Pragma("unroll")
#define FRAG(bufp, r, fc) (*(const bf16x8*)&(bufp)[(r) * 64 + ((((fc) ^ ((r) & 7))) << 3)])

#define LOAD_A(Ac, mh)                                                        \
    UNROLL for (int i4 = 0; i4 < 4; i4++)                                     \
    UNROLL for (int kk = 0; kk < 2; kk++)                                     \
        af[i4][kk] = FRAG(Ac, wr + (mh) * 64 + i4 * 16 + l16, kk * 4 + quad);

#define LOAD_B(Bc, nh)                                                        \
    UNROLL for (int j2 = 0; j2 < 2; j2++)                                     \
    UNROLL for (int kk = 0; kk < 2; kk++)                                     \
        bf[(nh) * 2 + j2][kk] = FRAG(Bc, wc + (nh) * 32 + j2 * 16 + l16, kk * 4 + quad);

#define MFMA_Q(mh, nh)                                                        \
    __builtin_amdgcn_s_barrier();                                             \
    asm volatile("s_waitcnt lgkmcnt(0)" ::: "memory");                        \
    __builtin_amdgcn_s_setprio(1);                                            \
    UNROLL for (int i4 = 0; i4 < 4; i4++)                                     \
    UNROLL for (int j2 = 0; j2 < 2; j2++)                                     \
    UNROLL for (int kk = 0; kk < 2; kk++)                                     \
        acc[(mh) * 4 + i4][(nh) * 2 + j2] = __builtin_amdgcn_mfma_f32_16x16x32_bf16( \
            af[i4][kk], bf[(nh) * 2 + j2][kk], acc[(mh) * 4 + i4][(nh) * 2 + j2], 0, 0, 0); \
    __builtin_amdgcn_s_setprio(0);

#define VM_WAIT4 asm volatile("s_waitcnt vmcnt(4)" ::: "memory");
#define BAR __builtin_amdgcn_s_barrier();

// stage one 128-row half-tile (rows [0,128) of gp) into lb; 2 gload16/lane
__device__ __forceinline__ void stage128(const u16* gp, size_t ldg, u16* lb,
                                         int wave, int sr, int csrc) {
    gload16(gp + (size_t)(wave * 8 + sr) * ldg + csrc, lb + wave * 8 * 64);
    gload16(gp + (size_t)(wave * 8 + sr + 64) * ldg + csrc, lb + (wave * 8 + 64) * 64);
}

// ---------------- GEMM 1: gate_up + GLU epilogue (rw folded in) ----------------

__global__ __launch_bounds__(512, 2) void k_gemm_gateup(
    const u16* __restrict__ xb,    // [T][H] bf16
    const u16* __restrict__ wP,    // [E][4096][H] bf16, gate/up 16-col groups
    const float* __restrict__ gub, // [E][2D] fp32 interleaved
    const float* __restrict__ rw,  // [T][E] fp32
    u16* __restrict__ fused)       // [E][T][D] bf16
{
    // grid 1024; XCD k owns n-tiles {2k,2k+1} for all e; t fastest on-XCD.
    const int id = blockIdx.x;
    const int xcd = id & 7;
    const int local = id >> 3;            // 0..127
    const int e = local >> 4;
    const int rem = local & 15;
    const int t0 = (rem & 7) * 256;
    const int n0 = (xcd * 2 + (rem >> 3)) * 256;

    __shared__ u16 As[2 * 256 * 64];
    __shared__ u16 Bs[2 * 256 * 64];
    u16* As0 = As;  u16* As1 = As + 256 * 64;
    u16* Bs0 = Bs;  u16* Bs1 = Bs + 256 * 64;

    const int tid = threadIdx.x;
    const int lane = tid & 63;
    const int wave = tid >> 6;
    const int wr = (wave >> 2) * 128;
    const int wc = (wave & 3) * 64;
    const int l16 = lane & 15;
    const int quad = lane >> 4;
    const int sr = lane >> 3;
    const int csrc = ((lane & 7) ^ sr) * 8;

    const u16* Ab = xb + (size_t)t0 * H_;
    const u16* Bb = wP + ((size_t)e * N2_ + n0) * H_;
#define APTR1(kt) (Ab + (kt) * 64)
#define BPTR1(kt) (Bb + (kt) * 64)

    f32x4 acc[8][4];
    const f32x4 vzero = {0.f, 0.f, 0.f, 0.f};
    UNROLL for (int i = 0; i < 8; i++)
        UNROLL for (int j = 0; j < 4; j++) acc[i][j] = vzero;
    bf16x8 af[4][2], bf[4][2];

    // prologue: buf0.A + buf0.B (kt0), buf1.B (kt1); allow buf1.B in flight
    stage128(APTR1(0), H_, As0, wave, sr, csrc);
    stage128(APTR1(0) + (size_t)128 * H_, H_, As0 + 128 * 64, wave, sr, csrc);
    stage128(BPTR1(0), H_, Bs0, wave, sr, csrc);
    stage128(BPTR1(0) + (size_t)128 * H_, H_, Bs0 + 128 * 64, wave, sr, csrc);
    stage128(BPTR1(1), H_, Bs1, wave, sr, csrc);
    stage128(BPTR1(1) + (size_t)128 * H_, H_, Bs1 + 128 * 64, wave, sr, csrc);
    VM_WAIT4; BAR;

    const int NT = H_ / 64;               // 32
    for (int it = 0; it < NT / 2; ++it) {
        const int ka = 2 * it + 1;
        const int kb = (2 * it + 2 < NT) ? 2 * it + 2 : NT - 1;
        const int kc = (2 * it + 3 < NT) ? 2 * it + 3 : NT - 1;
        // ph1 (buf0: mh0,nh0)
        LOAD_A(As0, 0); LOAD_B(Bs0, 0);
        stage128(APTR1(ka), H_, As1, wave, sr, csrc);
        MFMA_Q(0, 0); BAR;
        // ph2 (mh0,nh1)
        LOAD_B(Bs0, 1);
        stage128(APTR1(ka) + (size_t)128 * H_, H_, As1 + 128 * 64, wave, sr, csrc);
        MFMA_Q(0, 1); BAR;
        // ph3 (mh1,nh0) — Bs0 reads done at ph2, safe to restage
        LOAD_A(As0, 1);
        stage128(BPTR1(kb), H_, Bs0, wave, sr, csrc);
        MFMA_Q(1, 0); BAR;
        // ph4 (mh1,nh1)
        stage128(BPTR1(kb) + (size_t)128 * H_, H_, Bs0 + 128 * 64, wave, sr, csrc);
        MFMA_Q(1, 1); VM_WAIT4; BAR;
        // ph5 (buf1: mh0,nh0) — As0 reads done at ph3
        LOAD_A(As1, 0); LOAD_B(Bs1, 0);
        stage128(APTR1(kb), H_, As0, wave, sr, csrc);
        MFMA_Q(0, 0); BAR;
        // ph6 (mh0,nh1)
        LOAD_B(Bs1, 1);
        stage128(APTR1(kb) + (size_t)128 * H_, H_, As0 + 128 * 64, wave, sr, csrc);
        MFMA_Q(0, 1); BAR;
        // ph7 (mh1,nh0) — Bs1 reads done at ph6
        LOAD_A(As1, 1);
        stage128(BPTR1(kc), H_, Bs1, wave, sr, csrc);
        MFMA_Q(1, 0); BAR;
        // ph8 (mh1,nh1)
        stage128(BPTR1(kc) + (size_t)128 * H_, H_, Bs1 + 128 * 64, wave, sr, csrc);
        MFMA_Q(1, 1); VM_WAIT4; BAR;
    }
#undef APTR1
#undef BPTR1

    // epilogue: n-frag pair (2m, 2m+1) = (gate, up) for the same d
    const float* gbe = gub + e * N2_;
    const int dbase = (n0 + wc) >> 1;
    u16* fbase = fused + (size_t)e * T_ * D_;
    UNROLL for (int i = 0; i < 8; i++) {
        UNROLL for (int m = 0; m < 2; m++) {
            const int d = dbase + m * 16 + l16;
            const float bg = gbe[2 * d];
            const float bu = gbe[2 * d + 1];
            UNROLL for (int r = 0; r < 4; r++) {
                const int row = t0 + wr + i * 16 + quad * 4 + r;
                float g = acc[i][2 * m][r] + bg;
                float u = acc[i][2 * m + 1][r] + bu;
                g = fminf(g, 7.0f);
                u = fminf(fmaxf(u, -7.0f), 7.0f);
                float glu = g / (1.0f + __expf(-1.702f * g));
                float f = (u + 1.0f) * glu * rw[row * E_ + e];
                fbase[(size_t)row * D_ + d] = f2bf(f);
            }
        }
    }
}

// ---------------- GEMM 2: down proj, experts-in-K (K=4096), 256x256 --------

__global__ __launch_bounds__(512, 2) void k_gemm_down(
    const u16* __restrict__ fused, // [E][T][D] bf16 (rw-scaled)
    const u16* __restrict__ wdT,   // [E][H][D] bf16
    float* __restrict__ pout)      // [4][T][H] fp32 partials
{
    // grid 256 = exactly 1 block/CU; XCD k owns h-tile k; t fastest.
    const int id = blockIdx.x;
    const int xcd = id & 7;
    const int local = id >> 3;           // 0..31
    const int g = local >> 3;            // expert pair
    const int t0 = (local & 7) * 256;
    const int h0 = xcd * 256;
    const int e0 = g * 2;

    __shared__ u16 As[2 * 256 * 64];
    __shared__ u16 Bs[2 * 256 * 64];
    u16* As0 = As;  u16* As1 = As + 256 * 64;
    u16* Bs0 = Bs;  u16* Bs1 = Bs + 256 * 64;

    const int tid = threadIdx.x;
    const int lane = tid & 63;
    const int wave = tid >> 6;
    const int wr = (wave >> 2) * 128;
    const int wc = (wave & 3) * 64;
    const int l16 = lane & 15;
    const int quad = lane >> 4;
    const int sr = lane >> 3;
    const int csrc = ((lane & 7) ^ sr) * 8;

#define APTR2(kt) (fused + ((size_t)(e0 + ((kt) >> 5)) * T_ + t0) * D_ + ((kt) & 31) * 64)
#define BPTR2(kt) (wdT + ((size_t)(e0 + ((kt) >> 5)) * H_ + h0) * D_ + ((kt) & 31) * 64)

    f32x4 acc[8][4];
    const f32x4 vzero = {0.f, 0.f, 0.f, 0.f};
    UNROLL for (int i = 0; i < 8; i++)
        UNROLL for (int j = 0; j < 4; j++) acc[i][j] = vzero;
    bf16x8 af[4][2], bf[4][2];

    stage128(APTR2(0), D_, As0, wave, sr, csrc);
    stage128(APTR2(0) + (size_t)128 * D_, D_, As0 + 128 * 64, wave, sr, csrc);
    stage128(BPTR2(0), D_, Bs0, wave, sr, csrc);
    stage128(BPTR2(0) + (size_t)128 * D_, D_, Bs0 + 128 * 64, wave, sr, csrc);
    stage128(BPTR2(1), D_, Bs1, wave, sr, csrc);
    stage128(BPTR2(1) + (size_t)128 * D_, D_, Bs1 + 128 * 64, wave, sr, csrc);
    VM_WAIT4; BAR;

    const int NT = 2 * (D_ / 64);        // 64 (2 experts in K)
    for (int it = 0; it < NT / 2; ++it) {
        const int ka = 2 * it + 1;
        const int kb = (2 * it + 2 < NT) ? 2 * it + 2 : NT - 1;
        const int kc = (2 * it + 3 < NT) ? 2 * it + 3 : NT - 1;
        // ph1
        LOAD_A(As0, 0); LOAD_B(Bs0, 0);
        stage128(APTR2(ka), D_, As1, wave, sr, csrc);
        MFMA_Q(0, 0); BAR;
        // ph2
        LOAD_B(Bs0, 1);
        stage128(APTR2(ka) + (size_t)128 * D_, D_, As1 + 128 * 64, wave, sr, csrc);
        MFMA_Q(0, 1); BAR;
        // ph3
        LOAD_A(As0, 1);
        stage128(BPTR2(kb), D_, Bs0, wave, sr, csrc);
        MFMA_Q(1, 0); BAR;
        // ph4
        stage128(BPTR2(kb) + (size_t)128 * D_, D_, Bs0 + 128 * 64, wave, sr, csrc);
        MFMA_Q(1, 1); VM_WAIT4; BAR;
        // ph5
        LOAD_A(As1, 0); LOAD_B(Bs1, 0);
        stage128(APTR2(kb), D_, As0, wave, sr, csrc);
        MFMA_Q(0, 0); BAR;
        // ph6
        LOAD_B(Bs1, 1);
        stage128(APTR2(kb) + (size_t)128 * D_, D_, As0 + 128 * 64, wave, sr, csrc);
        MFMA_Q(0, 1); BAR;
        // ph7
        LOAD_A(As1, 1);
        stage128(BPTR2(kc), D_, Bs1, wave, sr, csrc);
        MFMA_Q(1, 0); BAR;
        // ph8
        stage128(BPTR2(kc) + (size_t)128 * D_, D_, Bs1 + 128 * 64, wave, sr, csrc);
        MFMA_Q(1, 1); VM_WAIT4; BAR;
    }
#undef APTR2
#undef BPTR2

    float* po = pout + (size_t)g * T_ * H_;
    UNROLL for (int i = 0; i < 8; i++) {
        UNROLL for (int r = 0; r < 4; r++) {
            const int row = t0 + wr + i * 16 + quad * 4 + r;
            UNROLL for (int j = 0; j < 4; j++) {
                po[(size_t)row * H_ + h0 + wc + j * 16 + l16] = acc[i][j][r];
            }
        }
    }
}

// out[t][h] = sum_g pout[g] + sum_e rw[t][e] * down_b[e][h]   (float4)
__global__ __launch_bounds__(256) void k_combine(const float4* __restrict__ p,
                                                 const float* __restrict__ rw,
                                                 const float4* __restrict__ db,
                                                 float4* __restrict__ out) {
    int i = blockIdx.x * 256 + threadIdx.x;   // T_*H_/4 elements
    int t = i >> 9;                            // H_/4 = 512 float4 per row
    int h4 = i & 511;
    const size_t TH4 = (size_t)T_ * H_ / 4;
    float4 s0 = p[i], s1 = p[i + TH4], s2 = p[i + 2 * TH4], s3 = p[i + 3 * TH4];
    float4 a;
    a.x = s0.x + s1.x + s2.x + s3.x;
    a.y = s0.y + s1.y + s2.y + s3.y;
    a.z = s0.z + s1.z + s2.z + s3.z;
    a.w = s0.w + s1.w + s2.w + s3.w;
#pragma unroll
    for (int e = 0; e < E_; e++) {
        float w = rw[t * E_ + e];
        float4 b = db[e * (H_ / 4) + h4];
        a.x += w * b.x; a.y += w * b.y; a.z += w * b.z; a.w += w * b.w;
    }
    out[i] = a;
}

// ---------------- launch ----------------

extern "C" void kernel_launch(void* const* d_in, const int* in_sizes, int n_in,
                              void* d_out, int out_size, void* d_ws, size_t ws_size,
                              hipStream_t stream) {
    const float* x   = (const float*)d_in[0];   // [B,S,H]
    const float* rw  = (const float*)d_in[1];   // [T,E]
    const float* guw = (const float*)d_in[2];   // [E,H,2D]
    const float* gub = (const float*)d_in[3];   // [E,2D]
    const float* dww = (const float*)d_in[4];   // [E,D,H]
    const float* dwb = (const float*)d_in[5];   // [E,H]
    float* out = (float*)d_out;

    char* ws = (char*)d_ws;
    u16* xb    = (u16*)(ws);                      //   8 MB  [T][H]
    u16* wP    = (u16*)(ws + 8388608);            // 128 MB  [E][4096][H]
    u16* wdT   = (u16*)(ws + 142606336);          //  64 MB  [E][H][D]
    u16* fused = (u16*)(ws + 209715200);          //  64 MB  [E][T][D]
    // pout (64 MB fp32 [4][T][H]) reuses the wP region — dead after gemm1.
    float* pout = (float*)(ws + 8388608);

    k_convert_x<<<dim3((T_ * H_) / 4 / 256), 256, 0, stream>>>((const float4*)x, (ushort4*)xb);
    k_tr_gateup<<<dim3(H_ / 64, D_ / 64, E_), 256, 0, stream>>>(guw, wP);
    k_tr_down<<<dim3(D_ / 64, H_ / 64, E_), 256, 0, stream>>>(dww, wdT);
    k_gemm_gateup<<<dim3(1024), 512, 0, stream>>>(xb, wP, gub, rw, fused);
    k_gemm_down<<<dim3(256), 512, 0, stream>>>(fused, wdT, pout);
    k_combine<<<dim3((T_ * H_) / 4 / 256), 256, 0, stream>>>((const float4*)pout, rw, (const float4*)dwb, (float4*)out);
}